// Round 1
// baseline (653.225 us; speedup 1.0000x reference)
//
#include <hip/hip_runtime.h>
#include <math.h>

// Problem constants
#define NTOT   128      // batch n
#define HID_   256
#define NPOS   4096     // 64*64
#define CHUNK  512      // spatial positions per attention block
#define NCH    8        // 4096 / 512
#define GKC    256      // GEMM K-chunk (split-K)
#define PSTRIDE 744     // per (n,chunk) partial: 4 m + 4 l + 4*184 acc

// ---------------------------------------------------------------- spatial basis
// S[i][j][u*8+v] = cos((i+1)(u+1)pi/64) * cos((j+1)(v+1)pi/64)
__global__ __launch_bounds__(256) void k_sbasis(float* __restrict__ S) {
  int idx = blockIdx.x * 256 + threadIdx.x;   // < 64*64*64
  int s = idx & 63;
  int j = (idx >> 6) & 63;
  int i = idx >> 12;
  int u = s >> 3, v = s & 7;
  const float f = 3.14159265358979323846f / 64.f;
  S[idx] = cosf((float)((i + 1) * (u + 1)) * f) * cosf((float)((j + 1) * (v + 1)) * f);
}

// ---------------------------------------------------------------- split-K GEMM
// out_partial[z][m][j] = sum_{k in chunk z} A[m][k] * W[k][coff + j]
// A: (128, K) row-major. W: (K, ldw) row-major. coff = (*cptr) * cmul.
__global__ __launch_bounds__(256) void k_gemm(
    const float* __restrict__ A, const float* __restrict__ W,
    float* __restrict__ pbuf, int N, int K, int ldw,
    const int* __restrict__ cptr, int cmul) {
  __shared__ float Xs[8][GKC];
  const int t  = threadIdx.x;
  const int j  = blockIdx.x * 256 + t;
  const int m0 = blockIdx.y * 8;
  const int k0 = blockIdx.z * GKC;
  const int klen = min(GKC, K - k0);
  const int coff = cptr[0] * cmul;

  for (int idx = t; idx < 8 * klen; idx += 256) {
    int mi = idx / klen;
    int kk = idx - mi * klen;
    Xs[mi][kk] = A[(size_t)(m0 + mi) * K + k0 + kk];
  }
  __syncthreads();

  if (j < N) {
    float acc[8];
#pragma unroll
    for (int mi = 0; mi < 8; ++mi) acc[mi] = 0.f;
    const float* wp = W + (size_t)k0 * ldw + coff + j;
#pragma unroll 4
    for (int kk = 0; kk < klen; ++kk) {
      float wv = wp[(size_t)kk * ldw];
#pragma unroll
      for (int mi = 0; mi < 8; ++mi) acc[mi] = fmaf(Xs[mi][kk], wv, acc[mi]);
    }
    float* op = pbuf + ((size_t)blockIdx.z * NTOT + m0) * N + j;
#pragma unroll
    for (int mi = 0; mi < 8; ++mi) op[(size_t)mi * N] = acc[mi];
  }
}

// reduce split-K partials + bias (+optional relu)
__global__ __launch_bounds__(256) void k_reduce(
    const float* __restrict__ pbuf, const float* __restrict__ bias,
    float* __restrict__ out, int N, int nz, int act,
    const int* __restrict__ cptr, int cmul) {
  const int j = blockIdx.x * 256 + threadIdx.x;
  const int m = blockIdx.y;
  if (j >= N) return;
  float s = 0.f;
  for (int z = 0; z < nz; ++z) s += pbuf[((size_t)z * NTOT + m) * N + j];
  s += bias[cptr[0] * cmul + j];
  if (act) s = fmaxf(s, 0.f);
  out[(size_t)m * N + j] = s;
}

// ---------------------------------------------------------------- attention partial
// Per (n, chunk): logits over 512 positions x 4 queries, chunk-local softmax
// stats (m, l), and unnormalized weighted-V accumulation acc[4][184].
__global__ __launch_bounds__(256) void k_attn_part(
    const float* __restrict__ x, const float* __restrict__ S,
    const float* __restrict__ Qb, float* __restrict__ P) {
  const int n  = blockIdx.y;
  const int ch = blockIdx.x;
  const int t  = threadIdx.x;

  __shared__ float Qs[4][72];
  __shared__ __align__(16) float wlds[CHUNK][4];
  __shared__ float red[4][4];
  __shared__ float mfin[4], lfin[4];

  for (int idx = t; idx < 288; idx += 256) Qs[idx / 72][idx % 72] = Qb[(size_t)n * 288 + idx];
  __syncthreads();

  const int base = ch * CHUNK;
  const float* xp = x + (size_t)n * NPOS * 128;

  // ---- phase A: logits (reads x channels 0..7 + S) ----
  float lmax[4] = {-1e30f, -1e30f, -1e30f, -1e30f};
#pragma unroll
  for (int pp = 0; pp < 2; ++pp) {
    const int p   = pp * 256 + t;
    const int pos = base + p;
    const float4* xr = reinterpret_cast<const float4*>(xp + (size_t)pos * 128);
    float4 xa = xr[0], xb = xr[1];
    float lg[4];
#pragma unroll
    for (int q = 0; q < 4; ++q)
      lg[q] = xa.x * Qs[q][0] + xa.y * Qs[q][1] + xa.z * Qs[q][2] + xa.w * Qs[q][3]
            + xb.x * Qs[q][4] + xb.y * Qs[q][5] + xb.z * Qs[q][6] + xb.w * Qs[q][7];
    const float4* sr = reinterpret_cast<const float4*>(S + (size_t)pos * 64);
#pragma unroll
    for (int s4 = 0; s4 < 16; ++s4) {
      float4 sv = sr[s4];
#pragma unroll
      for (int q = 0; q < 4; ++q)
        lg[q] += sv.x * Qs[q][8 + 4 * s4] + sv.y * Qs[q][9 + 4 * s4]
               + sv.z * Qs[q][10 + 4 * s4] + sv.w * Qs[q][11 + 4 * s4];
    }
    *reinterpret_cast<float4*>(&wlds[p][0]) = make_float4(lg[0], lg[1], lg[2], lg[3]);
#pragma unroll
    for (int q = 0; q < 4; ++q) lmax[q] = fmaxf(lmax[q], lg[q]);
  }

  // block max per q
#pragma unroll
  for (int off = 32; off; off >>= 1)
#pragma unroll
    for (int q = 0; q < 4; ++q) lmax[q] = fmaxf(lmax[q], __shfl_xor(lmax[q], off));
  if ((t & 63) == 0) {
    int wid = t >> 6;
#pragma unroll
    for (int q = 0; q < 4; ++q) red[q][wid] = lmax[q];
  }
  __syncthreads();
  if (t < 4) mfin[t] = fmaxf(fmaxf(red[t][0], red[t][1]), fmaxf(red[t][2], red[t][3]));
  __syncthreads();

  // exp + block sum per q
  float lsum[4] = {0.f, 0.f, 0.f, 0.f};
#pragma unroll
  for (int pp = 0; pp < 2; ++pp) {
    const int p = pp * 256 + t;
    float4 wv = *reinterpret_cast<float4*>(&wlds[p][0]);
    wv.x = __expf(wv.x - mfin[0]);
    wv.y = __expf(wv.y - mfin[1]);
    wv.z = __expf(wv.z - mfin[2]);
    wv.w = __expf(wv.w - mfin[3]);
    *reinterpret_cast<float4*>(&wlds[p][0]) = wv;
    lsum[0] += wv.x; lsum[1] += wv.y; lsum[2] += wv.z; lsum[3] += wv.w;
  }
#pragma unroll
  for (int off = 32; off; off >>= 1)
#pragma unroll
    for (int q = 0; q < 4; ++q) lsum[q] += __shfl_xor(lsum[q], off);
  if ((t & 63) == 0) {
    int wid = t >> 6;
#pragma unroll
    for (int q = 0; q < 4; ++q) red[q][wid] = lsum[q];
  }
  __syncthreads();
  if (t < 4) lfin[t] = red[t][0] + red[t][1] + red[t][2] + red[t][3];
  __syncthreads();

  // ---- phase B: weighted V accumulation (reads x channels 8..127 + S) ----
  float a0 = 0.f, a1 = 0.f, a2 = 0.f, a3 = 0.f;
  if (t < 184) {
    const int d = t;
    const float* vp;
    int stride;
    if (d < 120) { vp = xp + (size_t)base * 128 + 8 + d; stride = 128; }
    else         { vp = S  + (size_t)base * 64  + (d - 120); stride = 64; }
    for (int p = 0; p < CHUNK; p += 4) {
      float v0 = vp[(size_t)(p + 0) * stride];
      float v1 = vp[(size_t)(p + 1) * stride];
      float v2 = vp[(size_t)(p + 2) * stride];
      float v3 = vp[(size_t)(p + 3) * stride];
      float4 w0 = *reinterpret_cast<const float4*>(&wlds[p + 0][0]);
      float4 w1 = *reinterpret_cast<const float4*>(&wlds[p + 1][0]);
      float4 w2 = *reinterpret_cast<const float4*>(&wlds[p + 2][0]);
      float4 w3 = *reinterpret_cast<const float4*>(&wlds[p + 3][0]);
      a0 += w0.x * v0 + w1.x * v1 + w2.x * v2 + w3.x * v3;
      a1 += w0.y * v0 + w1.y * v1 + w2.y * v2 + w3.y * v3;
      a2 += w0.z * v0 + w1.z * v1 + w2.z * v2 + w3.z * v3;
      a3 += w0.w * v0 + w1.w * v1 + w2.w * v2 + w3.w * v3;
    }
  }

  const size_t po = ((size_t)n * NCH + ch) * PSTRIDE;
  if (t < 4) { P[po + t] = mfin[t]; P[po + 4 + t] = lfin[t]; }
  if (t < 184) {
    P[po + 8 + 0 * 184 + t] = a0;
    P[po + 8 + 1 * 184 + t] = a1;
    P[po + 8 + 2 * 184 + t] = a2;
    P[po + 8 + 3 * 184 + t] = a3;
  }
}

// ---------------------------------------------------------------- attention combine
// Merge 8 chunk partials with online-softmax rescale; assemble 1026-dim answer.
__global__ __launch_bounds__(256) void k_attn_comb(
    const float* __restrict__ P, const float* __restrict__ Qb,
    const float* __restrict__ r_prev, const float* __restrict__ a_prev,
    float* __restrict__ ans) {
  const int n = blockIdx.x, t = threadIdx.x;
  __shared__ float sc[NCH][4];
  if (t < 4) {
    const int q = t;
    float M = -1e30f;
    for (int c = 0; c < NCH; ++c) M = fmaxf(M, P[((size_t)n * NCH + c) * PSTRIDE + q]);
    float L = 0.f;
    for (int c = 0; c < NCH; ++c) {
      const size_t po = ((size_t)n * NCH + c) * PSTRIDE;
      L += P[po + 4 + q] * __expf(P[po + q] - M);
    }
    const float inv = 1.f / L;
    for (int c = 0; c < NCH; ++c) {
      const size_t po = ((size_t)n * NCH + c) * PSTRIDE;
      sc[c][q] = __expf(P[po + q] - M) * inv;
    }
  }
  __syncthreads();
  float* ap = ans + (size_t)n * 1026;
  for (int idx = t; idx < 1026; idx += 256) {
    float val;
    if (idx < 736) {
      const int q = idx / 184, d = idx - q * 184;
      float s = 0.f;
#pragma unroll
      for (int c = 0; c < NCH; ++c)
        s += P[((size_t)n * NCH + c) * PSTRIDE + 8 + q * 184 + d] * sc[c][q];
      val = s;
    } else if (idx < 1024) {
      val = Qb[(size_t)n * 288 + (idx - 736)];
    } else if (idx == 1024) {
      val = r_prev[n];
    } else {
      val = a_prev[n];
    }
    ap[idx] = val;
  }
}

// ---------------------------------------------------------------- LSTM + heads
// 2 samples per block; thread t owns hidden unit t (gate rows t, t+256, t+512, t+768).
__global__ __launch_bounds__(256) void k_lstm(
    const float* __restrict__ amlp, const float* __restrict__ hp, const float* __restrict__ cp,
    const float* __restrict__ w_ih, const float* __restrict__ w_hh,
    const float* __restrict__ b_ih, const float* __restrict__ b_hh,
    const float* __restrict__ p_w, const float* __restrict__ p_b,
    const float* __restrict__ v_w, const float* __restrict__ v_b,
    float* __restrict__ out) {
  const int t  = threadIdx.x;
  const int n0 = blockIdx.x * 2;
  __shared__ float xs[2][256], hs[2][256], h2[2][256];
  xs[0][t] = amlp[(size_t)n0 * 256 + t];
  xs[1][t] = amlp[(size_t)(n0 + 1) * 256 + t];
  hs[0][t] = hp[(size_t)n0 * 256 + t];
  hs[1][t] = hp[(size_t)(n0 + 1) * 256 + t];
  __syncthreads();

  float g0[4], g1[4];
#pragma unroll
  for (int gi = 0; gi < 4; ++gi) {
    const int row = gi * 256 + t;
    const float4* wi = reinterpret_cast<const float4*>(w_ih + (size_t)row * 256);
    const float4* wh = reinterpret_cast<const float4*>(w_hh + (size_t)row * 256);
    const float b = b_ih[row] + b_hh[row];
    float s0 = b, s1 = b;
    for (int k = 0; k < 64; ++k) {
      float4 a = wi[k], c = wh[k];
      const int k4 = k * 4;
      s0 += a.x * xs[0][k4] + a.y * xs[0][k4 + 1] + a.z * xs[0][k4 + 2] + a.w * xs[0][k4 + 3];
      s0 += c.x * hs[0][k4] + c.y * hs[0][k4 + 1] + c.z * hs[0][k4 + 2] + c.w * hs[0][k4 + 3];
      s1 += a.x * xs[1][k4] + a.y * xs[1][k4 + 1] + a.z * xs[1][k4 + 2] + a.w * xs[1][k4 + 3];
      s1 += c.x * hs[1][k4] + c.y * hs[1][k4 + 1] + c.z * hs[1][k4 + 2] + c.w * hs[1][k4 + 3];
    }
    g0[gi] = s0;
    g1[gi] = s1;
  }
  auto sig = [](float v) { return 1.f / (1.f + __expf(-v)); };
  {
    float c2 = sig(g0[1]) * cp[(size_t)n0 * 256 + t] + sig(g0[0]) * tanhf(g0[2]);
    h2[0][t] = sig(g0[3]) * tanhf(c2);
  }
  {
    float c2 = sig(g1[1]) * cp[(size_t)(n0 + 1) * 256 + t] + sig(g1[0]) * tanhf(g1[2]);
    h2[1][t] = sig(g1[3]) * tanhf(c2);
  }
  __syncthreads();
  if (t < 72) {
    const int si = t / 36, r = t % 36, iv = r / 18, j = r % 18;
    const float* W = iv ? v_w : p_w;
    const float* B = iv ? v_b : p_b;
    float s = B[j];
    for (int k = 0; k < 256; ++k) s += h2[si][k] * W[k * 18 + j];
    out[(size_t)iv * (NTOT * 18) + (size_t)(n0 + si) * 18 + j] = s;
  }
}

// ---------------------------------------------------------------- launch
extern "C" void kernel_launch(void* const* d_in, const int* in_sizes, int n_in,
                              void* d_out, int out_size, void* d_ws, size_t ws_size,
                              hipStream_t stream) {
  const float* x      = (const float*)d_in[0];
  const int*   cptr   = (const int*)d_in[1];
  const float* r_prev = (const float*)d_in[2];
  const float* a_prev = (const float*)d_in[3];
  const float* hprev  = (const float*)d_in[4];
  const float* cprev  = (const float*)d_in[5];
  const float* q_w0 = (const float*)d_in[6];
  const float* q_b0 = (const float*)d_in[7];
  const float* q_w1 = (const float*)d_in[8];
  const float* q_b1 = (const float*)d_in[9];
  const float* q_w2 = (const float*)d_in[10];
  const float* q_b2 = (const float*)d_in[11];
  const float* a_w0 = (const float*)d_in[12];
  const float* a_b0 = (const float*)d_in[13];
  const float* a_w1 = (const float*)d_in[14];
  const float* a_b1 = (const float*)d_in[15];
  const float* a_w2 = (const float*)d_in[16];
  const float* a_b2 = (const float*)d_in[17];
  const float* w_ih = (const float*)d_in[18];
  const float* w_hh = (const float*)d_in[19];
  const float* b_ih = (const float*)d_in[20];
  const float* b_hh = (const float*)d_in[21];
  const float* p_w  = (const float*)d_in[22];
  const float* p_b  = (const float*)d_in[23];
  const float* v_w  = (const float*)d_in[24];
  const float* v_b  = (const float*)d_in[25];
  float* out = (float*)d_out;
  float* ws  = (float*)d_ws;

  // workspace layout (floats)
  float* Sb  = ws;             // 262144   spatial basis (64*64*64)
  float* Qb  = Sb + 262144;    // 36864    Q chunk (128,4,72)
  float* t0  = Qb + 36864;     // 65536    mlp ping
  float* t1  = t0 + 65536;     // 65536    mlp pong
  float* pb  = t1 + 65536;     // 327680   split-K partials (5*128*512)
  float* Pp  = pb + 327680;    // 761856   attn partials (1024*744)
  float* ans = Pp + 761856;    // 131328   answer (128,1026)
  float* am  = ans + 131328;   // 32768    a-mlp out (128,256)

  k_sbasis<<<1024, 256, 0, stream>>>(Sb);

  // q-mlp: hprev(128,256) -> 512 -> 512 -> Q chunk (288 cols at offset c*288)
  k_gemm<<<dim3(2, 16, 1), 256, 0, stream>>>(hprev, q_w0, pb, 512, 256, 512, cptr, 0);
  k_reduce<<<dim3(2, 128), 256, 0, stream>>>(pb, q_b0, t0, 512, 1, 1, cptr, 0);
  k_gemm<<<dim3(2, 16, 2), 256, 0, stream>>>(t0, q_w1, pb, 512, 512, 512, cptr, 0);
  k_reduce<<<dim3(2, 128), 256, 0, stream>>>(pb, q_b1, t1, 512, 2, 1, cptr, 0);
  k_gemm<<<dim3(2, 16, 2), 256, 0, stream>>>(t1, q_w2, pb, 288, 512, 1152, cptr, 288);
  k_reduce<<<dim3(2, 128), 256, 0, stream>>>(pb, q_b2, Qb, 288, 2, 0, cptr, 288);

  // attention
  k_attn_part<<<dim3(NCH, NTOT), 256, 0, stream>>>(x, Sb, Qb, Pp);
  k_attn_comb<<<NTOT, 256, 0, stream>>>(Pp, Qb, r_prev, a_prev, ans);

  // a-mlp: ans(128,1026) -> 512 -> 512 -> 256
  k_gemm<<<dim3(2, 16, 5), 256, 0, stream>>>(ans, a_w0, pb, 512, 1026, 512, cptr, 0);
  k_reduce<<<dim3(2, 128), 256, 0, stream>>>(pb, a_b0, t0, 512, 5, 1, cptr, 0);
  k_gemm<<<dim3(2, 16, 2), 256, 0, stream>>>(t0, a_w1, pb, 512, 512, 512, cptr, 0);
  k_reduce<<<dim3(2, 128), 256, 0, stream>>>(pb, a_b1, t1, 512, 2, 1, cptr, 0);
  k_gemm<<<dim3(1, 16, 2), 256, 0, stream>>>(t1, a_w2, pb, 256, 512, 256, cptr, 0);
  k_reduce<<<dim3(1, 128), 256, 0, stream>>>(pb, a_b2, am, 256, 2, 0, cptr, 0);

  // LSTM + policy/value heads
  k_lstm<<<64, 256, 0, stream>>>(am, hprev, cprev, w_ih, w_hh, b_ih, b_hh,
                                 p_w, p_b, v_w, v_b, out);
}

// Round 2
// 322.777 us; speedup vs baseline: 2.0238x; 2.0238x over previous
//
#include <hip/hip_runtime.h>
#include <math.h>

// Problem constants
#define NTOT   128      // batch n
#define NPOS   4096     // 64*64
#define CHUNK  256      // spatial positions per attention block
#define NCH    16       // 4096 / 256
#define GKC    128      // GEMM K-chunk (split-K)
#define PSTRIDE 744     // per (n,chunk) partial: 4 m + 4 l + 4*184 acc

// ---------------------------------------------------------------- spatial basis
__global__ __launch_bounds__(256) void k_sbasis(float* __restrict__ S) {
  int idx = blockIdx.x * 256 + threadIdx.x;   // < 64*64*64
  int s = idx & 63;
  int j = (idx >> 6) & 63;
  int i = idx >> 12;
  int u = s >> 3, v = s & 7;
  const float f = 3.14159265358979323846f / 64.f;
  S[idx] = cosf((float)((i + 1) * (u + 1)) * f) * cosf((float)((j + 1) * (v + 1)) * f);
}

// ---------------------------------------------------------------- split-K GEMM
// pbuf[z][m][j] = sum_{k in chunk z} A[m][k] * W[k][coff + j]
__global__ __launch_bounds__(256) void k_gemm(
    const float* __restrict__ A, const float* __restrict__ W,
    float* __restrict__ pbuf, int N, int K, int ldw,
    const int* __restrict__ cptr, int cmul) {
  __shared__ float Xs[4][GKC];
  const int t  = threadIdx.x;
  const int j  = blockIdx.x * 256 + t;
  const int m0 = blockIdx.y * 4;
  const int k0 = blockIdx.z * GKC;
  const int klen = min(GKC, K - k0);
  const int coff = cptr[0] * cmul;

  for (int idx = t; idx < 4 * klen; idx += 256) {
    int mi = idx / klen;
    int kk = idx - mi * klen;
    Xs[mi][kk] = A[(size_t)(m0 + mi) * K + k0 + kk];
  }
  __syncthreads();

  if (j < N) {
    float acc[4];
#pragma unroll
    for (int mi = 0; mi < 4; ++mi) acc[mi] = 0.f;
    const float* wp = W + (size_t)k0 * ldw + coff + j;
#pragma unroll 8
    for (int kk = 0; kk < klen; ++kk) {
      float wv = wp[(size_t)kk * ldw];
#pragma unroll
      for (int mi = 0; mi < 4; ++mi) acc[mi] = fmaf(Xs[mi][kk], wv, acc[mi]);
    }
    float* op = pbuf + ((size_t)blockIdx.z * NTOT + m0) * N + j;
#pragma unroll
    for (int mi = 0; mi < 4; ++mi) op[(size_t)mi * N] = acc[mi];
  }
}

// reduce split-K partials + bias (+optional relu)
__global__ __launch_bounds__(256) void k_reduce(
    const float* __restrict__ pbuf, const float* __restrict__ bias,
    float* __restrict__ out, int N, int nz, int act,
    const int* __restrict__ cptr, int cmul) {
  const int j = blockIdx.x * 256 + threadIdx.x;
  const int m = blockIdx.y;
  if (j >= N) return;
  float s = 0.f;
  for (int z = 0; z < nz; ++z) s += pbuf[((size_t)z * NTOT + m) * N + j];
  s += bias[cptr[0] * cmul + j];
  if (act) s = fmaxf(s, 0.f);
  out[(size_t)m * N + j] = s;
}

// ---------------------------------------------------------------- attention partial
// Per (n, chunk of 256 positions): logits (4 q), chunk-local softmax stats,
// unnormalized weighted-V accumulation acc[4][184].
__global__ __launch_bounds__(256) void k_attn_part(
    const float* __restrict__ x, const float* __restrict__ S,
    const float* __restrict__ Qb, float* __restrict__ P) {
  const int n  = blockIdx.y;
  const int ch = blockIdx.x;
  const int t  = threadIdx.x;
  const int wave = t >> 6, lane = t & 63;

  __shared__ float Qs[4][72];
  __shared__ float4 wlds[CHUNK];
  __shared__ float red[4][4];
  __shared__ float mfin[4], lfin[4];
  __shared__ float part[4][4][192];   // [wave][q][d]

  for (int idx = t; idx < 288; idx += 256) Qs[idx / 72][idx % 72] = Qb[(size_t)n * 288 + idx];
  __syncthreads();

  const int base = ch * CHUNK;
  const float* xp = x + (size_t)n * NPOS * 128;

  // ---- phase A: logits (x channels 0..7 + S), one position per thread ----
  const int pos = base + t;
  const float4* xr = reinterpret_cast<const float4*>(xp + (size_t)pos * 128);
  float4 xa = xr[0], xb = xr[1];
  float lg[4];
#pragma unroll
  for (int q = 0; q < 4; ++q)
    lg[q] = xa.x * Qs[q][0] + xa.y * Qs[q][1] + xa.z * Qs[q][2] + xa.w * Qs[q][3]
          + xb.x * Qs[q][4] + xb.y * Qs[q][5] + xb.z * Qs[q][6] + xb.w * Qs[q][7];
  const float4* sr = reinterpret_cast<const float4*>(S + (size_t)pos * 64);
#pragma unroll
  for (int s4 = 0; s4 < 16; ++s4) {
    float4 sv = sr[s4];
#pragma unroll
    for (int q = 0; q < 4; ++q)
      lg[q] += sv.x * Qs[q][8 + 4 * s4] + sv.y * Qs[q][9 + 4 * s4]
             + sv.z * Qs[q][10 + 4 * s4] + sv.w * Qs[q][11 + 4 * s4];
  }
  wlds[t] = make_float4(lg[0], lg[1], lg[2], lg[3]);

  float lmax[4];
#pragma unroll
  for (int q = 0; q < 4; ++q) lmax[q] = lg[q];
#pragma unroll
  for (int off = 32; off; off >>= 1)
#pragma unroll
    for (int q = 0; q < 4; ++q) lmax[q] = fmaxf(lmax[q], __shfl_xor(lmax[q], off));
  if (lane == 0)
#pragma unroll
    for (int q = 0; q < 4; ++q) red[q][wave] = lmax[q];
  __syncthreads();
  if (t < 4) mfin[t] = fmaxf(fmaxf(red[t][0], red[t][1]), fmaxf(red[t][2], red[t][3]));
  __syncthreads();

  float4 wv = wlds[t];
  wv.x = __expf(wv.x - mfin[0]);
  wv.y = __expf(wv.y - mfin[1]);
  wv.z = __expf(wv.z - mfin[2]);
  wv.w = __expf(wv.w - mfin[3]);
  wlds[t] = wv;
  float lsum[4] = {wv.x, wv.y, wv.z, wv.w};
#pragma unroll
  for (int off = 32; off; off >>= 1)
#pragma unroll
    for (int q = 0; q < 4; ++q) lsum[q] += __shfl_xor(lsum[q], off);
  if (lane == 0)
#pragma unroll
    for (int q = 0; q < 4; ++q) red[q][wave] = lsum[q];
  __syncthreads();
  if (t < 4) lfin[t] = red[t][0] + red[t][1] + red[t][2] + red[t][3];
  __syncthreads();   // also makes all wlds weights visible to all waves

  // ---- phase B: weighted V accumulation ----
  // wave w handles positions [w*64, w*64+64); lane owns d = lane, 64+lane, 128+lane
  const int pbeg = wave * 64;
  const float* vp0;
  const float* vp1;
  const float* vp2;
  int s0, s1, s2;
  {
    const int d0 = lane;                 // 0..63  -> x channel 8+d0
    vp0 = xp + (size_t)(base + pbeg) * 128 + 8 + d0; s0 = 128;
    const int d1 = 64 + lane;            // 64..127
    if (d1 < 120) { vp1 = xp + (size_t)(base + pbeg) * 128 + 8 + d1; s1 = 128; }
    else          { vp1 = S  + (size_t)(base + pbeg) * 64 + (d1 - 120); s1 = 64; }
    const int d2 = 128 + lane;           // 128..191 (valid < 184)
    if (d2 < 184) { vp2 = S  + (size_t)(base + pbeg) * 64 + (d2 - 120); s2 = 64; }
    else          { vp2 = S;  s2 = 0; }  // dummy broadcast, unused
  }
  float a0[4] = {0.f, 0.f, 0.f, 0.f};
  float a1[4] = {0.f, 0.f, 0.f, 0.f};
  float a2[4] = {0.f, 0.f, 0.f, 0.f};
#pragma unroll 4
  for (int p = 0; p < 64; ++p) {
    float4 w = wlds[pbeg + p];
    float v0 = vp0[p * s0];
    float v1 = vp1[p * s1];
    float v2 = vp2[p * s2];
    a0[0] += w.x * v0; a0[1] += w.y * v0; a0[2] += w.z * v0; a0[3] += w.w * v0;
    a1[0] += w.x * v1; a1[1] += w.y * v1; a1[2] += w.z * v1; a1[3] += w.w * v1;
    a2[0] += w.x * v2; a2[1] += w.y * v2; a2[2] += w.z * v2; a2[3] += w.w * v2;
  }
#pragma unroll
  for (int q = 0; q < 4; ++q) {
    part[wave][q][lane]      = a0[q];
    part[wave][q][64 + lane] = a1[q];
    if (lane < 56) part[wave][q][128 + lane] = a2[q];
  }
  __syncthreads();

  const size_t po = ((size_t)n * NCH + ch) * PSTRIDE;
  if (t < 4) { P[po + t] = mfin[t]; P[po + 4 + t] = lfin[t]; }
  for (int idx = t; idx < 736; idx += 256) {
    const int q = idx / 184, d = idx - q * 184;
    P[po + 8 + idx] = part[0][q][d] + part[1][q][d] + part[2][q][d] + part[3][q][d];
  }
}

// ---------------------------------------------------------------- attention combine
__global__ __launch_bounds__(256) void k_attn_comb(
    const float* __restrict__ P, const float* __restrict__ Qb,
    const float* __restrict__ r_prev, const float* __restrict__ a_prev,
    float* __restrict__ ans) {
  const int n = blockIdx.x, t = threadIdx.x;
  __shared__ float sc[NCH][4];
  if (t < 4) {
    const int q = t;
    float M = -1e30f;
    for (int c = 0; c < NCH; ++c) M = fmaxf(M, P[((size_t)n * NCH + c) * PSTRIDE + q]);
    float L = 0.f;
    for (int c = 0; c < NCH; ++c) {
      const size_t po = ((size_t)n * NCH + c) * PSTRIDE;
      L += P[po + 4 + q] * __expf(P[po + q] - M);
    }
    const float inv = 1.f / L;
    for (int c = 0; c < NCH; ++c) {
      const size_t po = ((size_t)n * NCH + c) * PSTRIDE;
      sc[c][q] = __expf(P[po + q] - M) * inv;
    }
  }
  __syncthreads();
  float* ap = ans + (size_t)n * 1026;
  for (int idx = t; idx < 1026; idx += 256) {
    float val;
    if (idx < 736) {
      const int q = idx / 184, d = idx - q * 184;
      float s = 0.f;
#pragma unroll
      for (int c = 0; c < NCH; ++c)
        s += P[((size_t)n * NCH + c) * PSTRIDE + 8 + q * 184 + d] * sc[c][q];
      val = s;
    } else if (idx < 1024) {
      val = Qb[(size_t)n * 288 + (idx - 736)];
    } else if (idx == 1024) {
      val = r_prev[n];
    } else {
      val = a_prev[n];
    }
    ap[idx] = val;
  }
}

// ---------------------------------------------------------------- LSTM gates
// grid (64 n-pairs, 16 row-groups of 64); 256 threads = 64 rows x 4 k-quarters
__global__ __launch_bounds__(256) void k_gates(
    const float* __restrict__ am, const float* __restrict__ hp,
    const float* __restrict__ w_ih, const float* __restrict__ w_hh,
    const float* __restrict__ b_ih, const float* __restrict__ b_hh,
    float* __restrict__ gbuf) {
  const int t = threadIdx.x;
  const int n0 = blockIdx.x * 2;
  const int r0 = blockIdx.y * 64;
  __shared__ float xs[2][256], hs[2][256];
  __shared__ float red[64][4][5];
  xs[0][t] = am[(size_t)n0 * 256 + t];
  xs[1][t] = am[(size_t)(n0 + 1) * 256 + t];
  hs[0][t] = hp[(size_t)n0 * 256 + t];
  hs[1][t] = hp[(size_t)(n0 + 1) * 256 + t];
  __syncthreads();
  const int r = t >> 2, kq = t & 3;
  const int row = r0 + r;
  const float4* wi = reinterpret_cast<const float4*>(w_ih + (size_t)row * 256 + kq * 64);
  const float4* wh = reinterpret_cast<const float4*>(w_hh + (size_t)row * 256 + kq * 64);
  float s00 = 0.f, s01 = 0.f, s10 = 0.f, s11 = 0.f;
#pragma unroll
  for (int i = 0; i < 16; ++i) {
    float4 a = wi[i], b = wh[i];
    const int k4 = kq * 64 + i * 4;
    s00 += a.x * xs[0][k4] + a.y * xs[0][k4 + 1] + a.z * xs[0][k4 + 2] + a.w * xs[0][k4 + 3];
    s01 += a.x * xs[1][k4] + a.y * xs[1][k4 + 1] + a.z * xs[1][k4 + 2] + a.w * xs[1][k4 + 3];
    s10 += b.x * hs[0][k4] + b.y * hs[0][k4 + 1] + b.z * hs[0][k4 + 2] + b.w * hs[0][k4 + 3];
    s11 += b.x * hs[1][k4] + b.y * hs[1][k4 + 1] + b.z * hs[1][k4 + 2] + b.w * hs[1][k4 + 3];
  }
  red[r][kq][0] = s00; red[r][kq][1] = s01; red[r][kq][2] = s10; red[r][kq][3] = s11;
  __syncthreads();
  if (t < 128) {
    const int rr = t >> 1, s = t & 1;
    float g = b_ih[r0 + rr] + b_hh[r0 + rr];
#pragma unroll
    for (int k = 0; k < 4; ++k) g += red[rr][k][s] + red[rr][k][2 + s];
    gbuf[(size_t)(n0 + s) * 1024 + r0 + rr] = g;
  }
}

// ---------------------------------------------------------------- LSTM elementwise + heads
__global__ __launch_bounds__(256) void k_lstm2(
    const float* __restrict__ gbuf, const float* __restrict__ cp,
    const float* __restrict__ p_w, const float* __restrict__ p_b,
    const float* __restrict__ v_w, const float* __restrict__ v_b,
    float* __restrict__ out) {
  const int t = threadIdx.x;
  const int n0 = blockIdx.x * 2;
  __shared__ float h2[2][256];
#pragma unroll
  for (int s = 0; s < 2; ++s) {
    const size_t gb = (size_t)(n0 + s) * 1024;
    float gi = gbuf[gb + t], gf = gbuf[gb + 256 + t];
    float gg = gbuf[gb + 512 + t], go = gbuf[gb + 768 + t];
    float si = 1.f / (1.f + __expf(-gi));
    float sf = 1.f / (1.f + __expf(-gf));
    float so = 1.f / (1.f + __expf(-go));
    float c2 = sf * cp[(size_t)(n0 + s) * 256 + t] + si * tanhf(gg);
    h2[s][t] = so * tanhf(c2);
  }
  __syncthreads();
  if (t < 72) {
    const int si = t / 36, r = t % 36, iv = r / 18, j = r % 18;
    const float* W = iv ? v_w : p_w;
    const float* B = iv ? v_b : p_b;
    float s = B[j];
    for (int k = 0; k < 256; ++k) s += h2[si][k] * W[k * 18 + j];
    out[(size_t)iv * (NTOT * 18) + (size_t)(n0 + si) * 18 + j] = s;
  }
}

// ---------------------------------------------------------------- launch
extern "C" void kernel_launch(void* const* d_in, const int* in_sizes, int n_in,
                              void* d_out, int out_size, void* d_ws, size_t ws_size,
                              hipStream_t stream) {
  const float* x      = (const float*)d_in[0];
  const int*   cptr   = (const int*)d_in[1];
  const float* r_prev = (const float*)d_in[2];
  const float* a_prev = (const float*)d_in[3];
  const float* hprev  = (const float*)d_in[4];
  const float* cprev  = (const float*)d_in[5];
  const float* q_w0 = (const float*)d_in[6];
  const float* q_b0 = (const float*)d_in[7];
  const float* q_w1 = (const float*)d_in[8];
  const float* q_b1 = (const float*)d_in[9];
  const float* q_w2 = (const float*)d_in[10];
  const float* q_b2 = (const float*)d_in[11];
  const float* a_w0 = (const float*)d_in[12];
  const float* a_b0 = (const float*)d_in[13];
  const float* a_w1 = (const float*)d_in[14];
  const float* a_b1 = (const float*)d_in[15];
  const float* a_w2 = (const float*)d_in[16];
  const float* a_b2 = (const float*)d_in[17];
  const float* w_ih = (const float*)d_in[18];
  const float* w_hh = (const float*)d_in[19];
  const float* b_ih = (const float*)d_in[20];
  const float* b_hh = (const float*)d_in[21];
  const float* p_w  = (const float*)d_in[22];
  const float* p_b  = (const float*)d_in[23];
  const float* v_w  = (const float*)d_in[24];
  const float* v_b  = (const float*)d_in[25];
  float* out = (float*)d_out;
  float* ws  = (float*)d_ws;

  // workspace layout (floats); pb aliases Pp (disjoint lifetimes), gbuf aliases t0+t1
  float* Sb  = ws;              // 262144
  float* Qb  = Sb + 262144;     // 36864
  float* t0  = Qb + 36864;      // 65536
  float* t1  = t0 + 65536;      // 65536
  float* big = t1 + 65536;      // max(9*128*512, 2048*744) = 1523712
  float* pb  = big;
  float* Pp  = big;
  float* ans = big + 1523712;   // 131328
  float* am  = ans + 131328;    // 32768
  float* gbuf = t0;             // 131072 (t0+t1 dead by then)

  k_sbasis<<<1024, 256, 0, stream>>>(Sb);

  // q-mlp: hprev(128,256) -> 512 -> 512 -> Q chunk (288 cols at offset c*288)
  k_gemm<<<dim3(2, 32, 2), 256, 0, stream>>>(hprev, q_w0, pb, 512, 256, 512, cptr, 0);
  k_reduce<<<dim3(2, 128), 256, 0, stream>>>(pb, q_b0, t0, 512, 2, 1, cptr, 0);
  k_gemm<<<dim3(2, 32, 4), 256, 0, stream>>>(t0, q_w1, pb, 512, 512, 512, cptr, 0);
  k_reduce<<<dim3(2, 128), 256, 0, stream>>>(pb, q_b1, t1, 512, 4, 1, cptr, 0);
  k_gemm<<<dim3(2, 32, 4), 256, 0, stream>>>(t1, q_w2, pb, 288, 512, 1152, cptr, 288);
  k_reduce<<<dim3(2, 128), 256, 0, stream>>>(pb, q_b2, Qb, 288, 4, 0, cptr, 288);

  // attention
  k_attn_part<<<dim3(NCH, NTOT), 256, 0, stream>>>(x, Sb, Qb, Pp);
  k_attn_comb<<<NTOT, 256, 0, stream>>>(Pp, Qb, r_prev, a_prev, ans);

  // a-mlp: ans(128,1026) -> 512 -> 512 -> 256
  k_gemm<<<dim3(2, 32, 9), 256, 0, stream>>>(ans, a_w0, pb, 512, 1026, 512, cptr, 0);
  k_reduce<<<dim3(2, 128), 256, 0, stream>>>(pb, a_b0, t0, 512, 9, 1, cptr, 0);
  k_gemm<<<dim3(2, 32, 4), 256, 0, stream>>>(t0, a_w1, pb, 512, 512, 512, cptr, 0);
  k_reduce<<<dim3(2, 128), 256, 0, stream>>>(pb, a_b1, t1, 512, 4, 1, cptr, 0);
  k_gemm<<<dim3(1, 32, 4), 256, 0, stream>>>(t1, a_w2, pb, 256, 512, 256, cptr, 0);
  k_reduce<<<dim3(1, 128), 256, 0, stream>>>(pb, a_b2, am, 256, 4, 0, cptr, 0);

  // LSTM + heads
  k_gates<<<dim3(64, 16), 256, 0, stream>>>(am, hprev, w_ih, w_hh, b_ih, b_hh, gbuf);
  k_lstm2<<<64, 256, 0, stream>>>(gbuf, cprev, p_w, p_b, v_w, v_b, out);
}

// Round 3
// 310.821 us; speedup vs baseline: 2.1016x; 1.0385x over previous
//
#include <hip/hip_runtime.h>
#include <math.h>

// Problem constants
#define NTOT   128      // batch n
#define NPOS   4096     // 64*64
#define CHUNK  256      // spatial positions per attention block
#define NCH    16       // 4096 / 256
#define GKC    128      // GEMM K-chunk (split-K)
#define PSTRIDE 744     // per (n,chunk) partial: 4 m + 4 l + 4*184 acc

// ---------------------------------------------------------------- spatial basis
__global__ __launch_bounds__(256) void k_sbasis(float* __restrict__ S) {
  int idx = blockIdx.x * 256 + threadIdx.x;   // < 64*64*64
  int s = idx & 63;
  int j = (idx >> 6) & 63;
  int i = idx >> 12;
  int u = s >> 3, v = s & 7;
  const float f = 3.14159265358979323846f / 64.f;
  S[idx] = cosf((float)((i + 1) * (u + 1)) * f) * cosf((float)((j + 1) * (v + 1)) * f);
}

// ---------------------------------------------------------------- split-K GEMM with fused A-reduce
// A_eff[m][k] = Ad ? Ad[m][k] : act(sum_z pA[z][m][k] + biasA[k])
// pbuf[z][m][j] = sum_{k in chunk z} A_eff[m][k] * W[k][coff + j]
__global__ __launch_bounds__(256) void k_gemm(
    const float* __restrict__ Ad, const float* __restrict__ pA,
    const float* __restrict__ biasA, int nzA, int reluA,
    const float* __restrict__ W, float* __restrict__ pbuf,
    int N, int K, int ldw, const int* __restrict__ cptr, int cmul) {
  __shared__ float Xs[4][GKC];
  const int t  = threadIdx.x;
  const int j  = blockIdx.x * 256 + t;
  const int m0 = blockIdx.y * 4;
  const int k0 = blockIdx.z * GKC;
  const int klen = min(GKC, K - k0);
  const int coff = cptr[0] * cmul;

  for (int idx = t; idx < 4 * klen; idx += 256) {
    int mi = idx / klen;
    int kk = idx - mi * klen;
    int col = k0 + kk;
    float s;
    if (Ad) {
      s = Ad[(size_t)(m0 + mi) * K + col];
    } else {
      s = biasA[col];
      for (int z = 0; z < nzA; ++z) s += pA[((size_t)z * NTOT + m0 + mi) * K + col];
      if (reluA) s = fmaxf(s, 0.f);
    }
    Xs[mi][kk] = s;
  }
  __syncthreads();

  if (j < N) {
    float acc[4];
#pragma unroll
    for (int mi = 0; mi < 4; ++mi) acc[mi] = 0.f;
    const float* wp = W + (size_t)k0 * ldw + coff + j;
#pragma unroll 8
    for (int kk = 0; kk < klen; ++kk) {
      float wv = wp[(size_t)kk * ldw];
#pragma unroll
      for (int mi = 0; mi < 4; ++mi) acc[mi] = fmaf(Xs[mi][kk], wv, acc[mi]);
    }
    float* op = pbuf + ((size_t)blockIdx.z * NTOT + m0) * N + j;
#pragma unroll
    for (int mi = 0; mi < 4; ++mi) op[(size_t)mi * N] = acc[mi];
  }
}

// ---------------------------------------------------------------- attention partial
// Per (n, chunk of 256 positions). Q is reduced in-block from pQ partials.
__global__ __launch_bounds__(256) void k_attn_part(
    const float* __restrict__ x, const float* __restrict__ S,
    const float* __restrict__ pQ, const float* __restrict__ q_b2,
    const int* __restrict__ cptr, float* __restrict__ P) {
  const int n  = blockIdx.y;
  const int ch = blockIdx.x;
  const int t  = threadIdx.x;
  const int wave = t >> 6, lane = t & 63;

  __shared__ float Qs[4][72];
  __shared__ float4 wlds[CHUNK];
  __shared__ float red[4][4];
  __shared__ float mfin[4], lfin[4];
  __shared__ __align__(16) float part[4][4][192];   // [wave][q][d], padded

  {
    const int coff = cptr[0] * 288;
    for (int idx = t; idx < 288; idx += 256) {
      float s = q_b2[coff + idx];
#pragma unroll
      for (int z = 0; z < 4; ++z) s += pQ[((size_t)z * NTOT + n) * 288 + idx];
      Qs[idx / 72][idx % 72] = s;
    }
  }
  __syncthreads();

  const int base = ch * CHUNK;
  const float* xp = x + (size_t)n * NPOS * 128;

  // ---- phase A: logits (x channels 0..7 + S), one position per thread ----
  const int pos = base + t;
  const float4* xr = reinterpret_cast<const float4*>(xp + (size_t)pos * 128);
  float4 xa = xr[0], xb = xr[1];
  float lg[4];
#pragma unroll
  for (int q = 0; q < 4; ++q)
    lg[q] = xa.x * Qs[q][0] + xa.y * Qs[q][1] + xa.z * Qs[q][2] + xa.w * Qs[q][3]
          + xb.x * Qs[q][4] + xb.y * Qs[q][5] + xb.z * Qs[q][6] + xb.w * Qs[q][7];
  const float4* sr = reinterpret_cast<const float4*>(S + (size_t)pos * 64);
#pragma unroll
  for (int s4 = 0; s4 < 16; ++s4) {
    float4 sv = sr[s4];
#pragma unroll
    for (int q = 0; q < 4; ++q)
      lg[q] += sv.x * Qs[q][8 + 4 * s4] + sv.y * Qs[q][9 + 4 * s4]
             + sv.z * Qs[q][10 + 4 * s4] + sv.w * Qs[q][11 + 4 * s4];
  }
  wlds[t] = make_float4(lg[0], lg[1], lg[2], lg[3]);

  float lmax[4];
#pragma unroll
  for (int q = 0; q < 4; ++q) lmax[q] = lg[q];
#pragma unroll
  for (int off = 32; off; off >>= 1)
#pragma unroll
    for (int q = 0; q < 4; ++q) lmax[q] = fmaxf(lmax[q], __shfl_xor(lmax[q], off));
  if (lane == 0)
#pragma unroll
    for (int q = 0; q < 4; ++q) red[q][wave] = lmax[q];
  __syncthreads();
  if (t < 4) mfin[t] = fmaxf(fmaxf(red[t][0], red[t][1]), fmaxf(red[t][2], red[t][3]));
  __syncthreads();

  float4 wv = wlds[t];
  wv.x = __expf(wv.x - mfin[0]);
  wv.y = __expf(wv.y - mfin[1]);
  wv.z = __expf(wv.z - mfin[2]);
  wv.w = __expf(wv.w - mfin[3]);
  wlds[t] = wv;
  float lsum[4] = {wv.x, wv.y, wv.z, wv.w};
#pragma unroll
  for (int off = 32; off; off >>= 1)
#pragma unroll
    for (int q = 0; q < 4; ++q) lsum[q] += __shfl_xor(lsum[q], off);
  if (lane == 0)
#pragma unroll
    for (int q = 0; q < 4; ++q) red[q][wave] = lsum[q];
  __syncthreads();
  if (t < 4) lfin[t] = red[t][0] + red[t][1] + red[t][2] + red[t][3];
  __syncthreads();   // also makes all wlds weights visible to all waves

  // ---- phase B: weighted V accumulation, float4 channel blocks ----
  // wave w: positions [w*64, w*64+64). lane<30: x ch 8+4l..+3 (d=4l..4l+3);
  // lane 30..45: S ch 4(l-30).. (d=4l..4l+3). lanes 46+ idle.
  const int pbeg = wave * 64;
  const bool active = lane < 46;
  const float* vbase = xp;
  int vstride = 0;
  if (lane < 30)      { vbase = xp + (size_t)(base + pbeg) * 128 + 8 + 4 * lane; vstride = 128; }
  else if (lane < 46) { vbase = S  + (size_t)(base + pbeg) * 64 + 4 * (lane - 30); vstride = 64; }

  float4 aq0 = make_float4(0.f, 0.f, 0.f, 0.f);
  float4 aq1 = aq0, aq2 = aq0, aq3 = aq0;
  if (active) {
#pragma unroll 4
    for (int p = 0; p < 64; ++p) {
      float4 w = wlds[pbeg + p];
      float4 v = *reinterpret_cast<const float4*>(vbase + (size_t)p * vstride);
      aq0.x += w.x * v.x; aq0.y += w.x * v.y; aq0.z += w.x * v.z; aq0.w += w.x * v.w;
      aq1.x += w.y * v.x; aq1.y += w.y * v.y; aq1.z += w.y * v.z; aq1.w += w.y * v.w;
      aq2.x += w.z * v.x; aq2.y += w.z * v.y; aq2.z += w.z * v.z; aq2.w += w.z * v.w;
      aq3.x += w.w * v.x; aq3.y += w.w * v.y; aq3.z += w.w * v.z; aq3.w += w.w * v.w;
    }
    *reinterpret_cast<float4*>(&part[wave][0][4 * lane]) = aq0;
    *reinterpret_cast<float4*>(&part[wave][1][4 * lane]) = aq1;
    *reinterpret_cast<float4*>(&part[wave][2][4 * lane]) = aq2;
    *reinterpret_cast<float4*>(&part[wave][3][4 * lane]) = aq3;
  }
  __syncthreads();

  const size_t po = ((size_t)n * NCH + ch) * PSTRIDE;
  if (t < 4) { P[po + t] = mfin[t]; P[po + 4 + t] = lfin[t]; }
  for (int idx = t; idx < 736; idx += 256) {
    const int q = idx / 184, d = idx - q * 184;
    P[po + 8 + idx] = part[0][q][d] + part[1][q][d] + part[2][q][d] + part[3][q][d];
  }
}

// ---------------------------------------------------------------- attention combine
__global__ __launch_bounds__(256) void k_attn_comb(
    const float* __restrict__ P, const float* __restrict__ pQ,
    const float* __restrict__ q_b2, const int* __restrict__ cptr,
    const float* __restrict__ r_prev, const float* __restrict__ a_prev,
    float* __restrict__ ans) {
  const int n = blockIdx.x, t = threadIdx.x;
  __shared__ float sc[NCH][4];
  if (t < 4) {
    const int q = t;
    float M = -1e30f;
    for (int c = 0; c < NCH; ++c) M = fmaxf(M, P[((size_t)n * NCH + c) * PSTRIDE + q]);
    float L = 0.f;
    for (int c = 0; c < NCH; ++c) {
      const size_t po = ((size_t)n * NCH + c) * PSTRIDE;
      L += P[po + 4 + q] * __expf(P[po + q] - M);
    }
    const float inv = 1.f / L;
    for (int c = 0; c < NCH; ++c) {
      const size_t po = ((size_t)n * NCH + c) * PSTRIDE;
      sc[c][q] = __expf(P[po + q] - M) * inv;
    }
  }
  __syncthreads();
  const int coff = cptr[0] * 288;
  float* ap = ans + (size_t)n * 1026;
  for (int idx = t; idx < 1026; idx += 256) {
    float val;
    if (idx < 736) {
      const int q = idx / 184, d = idx - q * 184;
      float s = 0.f;
#pragma unroll
      for (int c = 0; c < NCH; ++c)
        s += P[((size_t)n * NCH + c) * PSTRIDE + 8 + q * 184 + d] * sc[c][q];
      val = s;
    } else if (idx < 1024) {
      const int qi = idx - 736;
      float s = q_b2[coff + qi];
#pragma unroll
      for (int z = 0; z < 4; ++z) s += pQ[((size_t)z * NTOT + n) * 288 + qi];
      val = s;
    } else if (idx == 1024) {
      val = r_prev[n];
    } else {
      val = a_prev[n];
    }
    ap[idx] = val;
  }
}

// ---------------------------------------------------------------- LSTM gates (fused a-mlp out reduce)
// grid (64 n-pairs, 16 row-groups of 64); 256 threads = 64 rows x 4 k-quarters
__global__ __launch_bounds__(256) void k_gates(
    const float* __restrict__ pA, const float* __restrict__ biasA,
    const float* __restrict__ hp,
    const float* __restrict__ w_ih, const float* __restrict__ w_hh,
    const float* __restrict__ b_ih, const float* __restrict__ b_hh,
    float* __restrict__ gbuf) {
  const int t = threadIdx.x;
  const int n0 = blockIdx.x * 2;
  const int r0 = blockIdx.y * 64;
  __shared__ float xs[2][256], hs[2][256];
  __shared__ float red[64][4][5];
#pragma unroll
  for (int s = 0; s < 2; ++s) {
    float v = biasA[t];
#pragma unroll
    for (int z = 0; z < 4; ++z) v += pA[((size_t)z * NTOT + n0 + s) * 256 + t];
    xs[s][t] = v;
    hs[s][t] = hp[(size_t)(n0 + s) * 256 + t];
  }
  __syncthreads();
  const int r = t >> 2, kq = t & 3;
  const int row = r0 + r;
  const float4* wi = reinterpret_cast<const float4*>(w_ih + (size_t)row * 256 + kq * 64);
  const float4* wh = reinterpret_cast<const float4*>(w_hh + (size_t)row * 256 + kq * 64);
  float s00 = 0.f, s01 = 0.f, s10 = 0.f, s11 = 0.f;
#pragma unroll
  for (int i = 0; i < 16; ++i) {
    float4 a = wi[i], b = wh[i];
    const int k4 = kq * 64 + i * 4;
    s00 += a.x * xs[0][k4] + a.y * xs[0][k4 + 1] + a.z * xs[0][k4 + 2] + a.w * xs[0][k4 + 3];
    s01 += a.x * xs[1][k4] + a.y * xs[1][k4 + 1] + a.z * xs[1][k4 + 2] + a.w * xs[1][k4 + 3];
    s10 += b.x * hs[0][k4] + b.y * hs[0][k4 + 1] + b.z * hs[0][k4 + 2] + b.w * hs[0][k4 + 3];
    s11 += b.x * hs[1][k4] + b.y * hs[1][k4 + 1] + b.z * hs[1][k4 + 2] + b.w * hs[1][k4 + 3];
  }
  red[r][kq][0] = s00; red[r][kq][1] = s01; red[r][kq][2] = s10; red[r][kq][3] = s11;
  __syncthreads();
  if (t < 128) {
    const int rr = t >> 1, s = t & 1;
    float g = b_ih[r0 + rr] + b_hh[r0 + rr];
#pragma unroll
    for (int k = 0; k < 4; ++k) g += red[rr][k][s] + red[rr][k][2 + s];
    gbuf[(size_t)(n0 + s) * 1024 + r0 + rr] = g;
  }
}

// ---------------------------------------------------------------- LSTM elementwise + heads
__global__ __launch_bounds__(256) void k_lstm2(
    const float* __restrict__ gbuf, const float* __restrict__ cp,
    const float* __restrict__ p_w, const float* __restrict__ p_b,
    const float* __restrict__ v_w, const float* __restrict__ v_b,
    float* __restrict__ out) {
  const int t = threadIdx.x;
  const int n0 = blockIdx.x * 2;
  __shared__ float h2[2][256];
#pragma unroll
  for (int s = 0; s < 2; ++s) {
    const size_t gb = (size_t)(n0 + s) * 1024;
    float gi = gbuf[gb + t], gf = gbuf[gb + 256 + t];
    float gg = gbuf[gb + 512 + t], go = gbuf[gb + 768 + t];
    float si = 1.f / (1.f + __expf(-gi));
    float sf = 1.f / (1.f + __expf(-gf));
    float so = 1.f / (1.f + __expf(-go));
    float c2 = sf * cp[(size_t)(n0 + s) * 256 + t] + si * tanhf(gg);
    h2[s][t] = so * tanhf(c2);
  }
  __syncthreads();
  if (t < 72) {
    const int si = t / 36, r = t % 36, iv = r / 18, j = r % 18;
    const float* W = iv ? v_w : p_w;
    const float* B = iv ? v_b : p_b;
    float s = B[j];
    for (int k = 0; k < 256; ++k) s += h2[si][k] * W[k * 18 + j];
    out[(size_t)iv * (NTOT * 18) + (size_t)(n0 + si) * 18 + j] = s;
  }
}

// ---------------------------------------------------------------- launch
extern "C" void kernel_launch(void* const* d_in, const int* in_sizes, int n_in,
                              void* d_out, int out_size, void* d_ws, size_t ws_size,
                              hipStream_t stream) {
  const float* x      = (const float*)d_in[0];
  const int*   cptr   = (const int*)d_in[1];
  const float* r_prev = (const float*)d_in[2];
  const float* a_prev = (const float*)d_in[3];
  const float* hprev  = (const float*)d_in[4];
  const float* cprev  = (const float*)d_in[5];
  const float* q_w0 = (const float*)d_in[6];
  const float* q_b0 = (const float*)d_in[7];
  const float* q_w1 = (const float*)d_in[8];
  const float* q_b1 = (const float*)d_in[9];
  const float* q_w2 = (const float*)d_in[10];
  const float* q_b2 = (const float*)d_in[11];
  const float* a_w0 = (const float*)d_in[12];
  const float* a_b0 = (const float*)d_in[13];
  const float* a_w1 = (const float*)d_in[14];
  const float* a_b1 = (const float*)d_in[15];
  const float* a_w2 = (const float*)d_in[16];
  const float* a_b2 = (const float*)d_in[17];
  const float* w_ih = (const float*)d_in[18];
  const float* w_hh = (const float*)d_in[19];
  const float* b_ih = (const float*)d_in[20];
  const float* b_hh = (const float*)d_in[21];
  const float* p_w  = (const float*)d_in[22];
  const float* p_b  = (const float*)d_in[23];
  const float* v_w  = (const float*)d_in[24];
  const float* v_b  = (const float*)d_in[25];
  float* out = (float*)d_out;
  float* ws  = (float*)d_ws;

  // workspace layout (floats)
  float* Sb  = ws;                // 262144
  float* pQ  = Sb  + 262144;      // 147456  (4 x 128 x 288) q_w2 partials
  float* pb1 = pQ  + 147456;      // 589824  (9 x 128 x 512)
  float* pb2 = pb1 + 589824;      // 262144  (4 x 128 x 512)
  float* pb3 = pb2 + 262144;      // 131072  (4 x 128 x 256)
  float* Pp  = pb3 + 131072;      // 1523712 (2048 x 744) attn partials
  float* ans = Pp  + 1523712;     // 131328  (128 x 1026)
  float* gbuf= ans + 131328;      // 131072  (128 x 1024)

  k_sbasis<<<1024, 256, 0, stream>>>(Sb);

  // q-mlp: hprev(128,256) -> 512 -> 512 -> Q partials (288 cols at offset c*288)
  k_gemm<<<dim3(2, 32, 2), 256, 0, stream>>>(hprev, nullptr, nullptr, 0, 0,
                                             q_w0, pb1, 512, 256, 512, cptr, 0);
  k_gemm<<<dim3(2, 32, 4), 256, 0, stream>>>(nullptr, pb1, q_b0, 2, 1,
                                             q_w1, pb2, 512, 512, 512, cptr, 0);
  k_gemm<<<dim3(2, 32, 4), 256, 0, stream>>>(nullptr, pb2, q_b1, 4, 1,
                                             q_w2, pQ, 288, 512, 1152, cptr, 288);

  // attention (Q reduced in-block from pQ)
  k_attn_part<<<dim3(NCH, NTOT), 256, 0, stream>>>(x, Sb, pQ, q_b2, cptr, Pp);
  k_attn_comb<<<NTOT, 256, 0, stream>>>(Pp, pQ, q_b2, cptr, r_prev, a_prev, ans);

  // a-mlp: ans(128,1026) -> 512 -> 512 -> 256 (partials into pb3)
  k_gemm<<<dim3(2, 32, 9), 256, 0, stream>>>(ans, nullptr, nullptr, 0, 0,
                                             a_w0, pb1, 512, 1026, 512, cptr, 0);
  k_gemm<<<dim3(2, 32, 4), 256, 0, stream>>>(nullptr, pb1, a_b0, 9, 1,
                                             a_w1, pb2, 512, 512, 512, cptr, 0);
  k_gemm<<<dim3(1, 32, 4), 256, 0, stream>>>(nullptr, pb2, a_b1, 4, 1,
                                             a_w2, pb3, 256, 512, 256, cptr, 0);

  // LSTM + heads (am reduced in-block from pb3)
  k_gates<<<dim3(64, 16), 256, 0, stream>>>(pb3, a_b2, hprev, w_ih, w_hh, b_ih, b_hh, gbuf);
  k_lstm2<<<64, 256, 0, stream>>>(gbuf, cprev, p_w, p_b, v_w, v_b, out);
}

// Round 4
// 233.648 us; speedup vs baseline: 2.7958x; 1.3303x over previous
//
#include <hip/hip_runtime.h>
#include <math.h>

// Problem constants
#define NTOT   128      // batch n
#define NPOS   4096     // 64*64
#define CHUNK  256      // spatial positions per attention block
#define NCH    16       // 4096 / 256
#define PSTRIDE 744     // per (n,chunk) partial: 4 m + 4 l + 4*184 acc

// ---------------------------------------------------------------- spatial basis
__global__ __launch_bounds__(256) void k_sbasis(float* __restrict__ S) {
  int idx = blockIdx.x * 256 + threadIdx.x;   // < 64*64*64
  int s = idx & 63;
  int j = (idx >> 6) & 63;
  int i = idx >> 12;
  int u = s >> 3, v = s & 7;
  const float f = 3.14159265358979323846f / 64.f;
  S[idx] = cosf((float)((i + 1) * (u + 1)) * f) * cosf((float)((j + 1) * (v + 1)) * f);
}

// ---------------------------------------------------------------- split-K GEMM with fused A-reduce
// A_eff[m][k] = Ad ? Ad[m][k] : act(sum_z pA[z][m][k] + biasA[k])
// pbuf[z][m][j] = sum_{k in chunk z} A_eff[m][k] * W[k][coff + j]
__global__ __launch_bounds__(256) void k_gemm(
    const float* __restrict__ Ad, const float* __restrict__ pA,
    const float* __restrict__ biasA, int nzA, int reluA,
    const float* __restrict__ W, float* __restrict__ pbuf,
    int N, int K, int ldw, int gkc, const int* __restrict__ cptr, int cmul) {
  __shared__ float Xs[4][128];
  const int t  = threadIdx.x;
  const int j  = blockIdx.x * 256 + t;
  const int m0 = blockIdx.y * 4;
  const int k0 = blockIdx.z * gkc;
  const int klen = min(gkc, K - k0);
  const int coff = cptr[0] * cmul;

  for (int idx = t; idx < 4 * klen; idx += 256) {
    int mi = idx / klen;
    int kk = idx - mi * klen;
    int col = k0 + kk;
    float s;
    if (Ad) {
      s = Ad[(size_t)(m0 + mi) * K + col];
    } else {
      // 4-way partial sums: keep the z loads independent / in flight
      float s0 = biasA[col], s1 = 0.f, s2 = 0.f, s3 = 0.f;
      int z = 0;
      for (; z + 4 <= nzA; z += 4) {
        s0 += pA[((size_t)(z + 0) * NTOT + m0 + mi) * K + col];
        s1 += pA[((size_t)(z + 1) * NTOT + m0 + mi) * K + col];
        s2 += pA[((size_t)(z + 2) * NTOT + m0 + mi) * K + col];
        s3 += pA[((size_t)(z + 3) * NTOT + m0 + mi) * K + col];
      }
      for (; z < nzA; ++z) s0 += pA[((size_t)z * NTOT + m0 + mi) * K + col];
      s = (s0 + s1) + (s2 + s3);
      if (reluA) s = fmaxf(s, 0.f);
    }
    Xs[mi][kk] = s;
  }
  __syncthreads();

  if (j < N) {
    float acc[4];
#pragma unroll
    for (int mi = 0; mi < 4; ++mi) acc[mi] = 0.f;
    const float* wp = W + (size_t)k0 * ldw + coff + j;
#pragma unroll 16
    for (int kk = 0; kk < klen; ++kk) {
      float wv = wp[(size_t)kk * ldw];
#pragma unroll
      for (int mi = 0; mi < 4; ++mi) acc[mi] = fmaf(Xs[mi][kk], wv, acc[mi]);
    }
    float* op = pbuf + ((size_t)blockIdx.z * NTOT + m0) * N + j;
#pragma unroll
    for (int mi = 0; mi < 4; ++mi) op[(size_t)mi * N] = acc[mi];
  }
}

// ---------------------------------------------------------------- attention partial
// Per (n, chunk of 256 positions). Q reduced in-block from pQ partials (z=8).
__global__ __launch_bounds__(256) void k_attn_part(
    const float* __restrict__ x, const float* __restrict__ S,
    const float* __restrict__ pQ, const float* __restrict__ q_b2,
    const int* __restrict__ cptr, float* __restrict__ P) {
  const int n  = blockIdx.y;
  const int ch = blockIdx.x;
  const int t  = threadIdx.x;
  const int wave = t >> 6, lane = t & 63;

  __shared__ float Qs[4][72];
  __shared__ float4 wlds[CHUNK];
  __shared__ float red[4][4];
  __shared__ float mfin[4], lfin[4];
  __shared__ __align__(16) float part[4][4][192];   // [wave][q][d], padded

  {
    const int coff = cptr[0] * 288;
    for (int idx = t; idx < 288; idx += 256) {
      float s = q_b2[coff + idx];
#pragma unroll
      for (int z = 0; z < 8; ++z) s += pQ[((size_t)z * NTOT + n) * 288 + idx];
      Qs[idx / 72][idx % 72] = s;
    }
  }
  __syncthreads();

  const int base = ch * CHUNK;
  const float* xp = x + (size_t)n * NPOS * 128;

  // ---- phase A: logits (x channels 0..7 + S), one position per thread ----
  const int pos = base + t;
  const float4* xr = reinterpret_cast<const float4*>(xp + (size_t)pos * 128);
  float4 xa = xr[0], xb = xr[1];
  float lg[4];
#pragma unroll
  for (int q = 0; q < 4; ++q)
    lg[q] = xa.x * Qs[q][0] + xa.y * Qs[q][1] + xa.z * Qs[q][2] + xa.w * Qs[q][3]
          + xb.x * Qs[q][4] + xb.y * Qs[q][5] + xb.z * Qs[q][6] + xb.w * Qs[q][7];
  const float4* sr = reinterpret_cast<const float4*>(S + (size_t)pos * 64);
#pragma unroll
  for (int s4 = 0; s4 < 16; ++s4) {
    float4 sv = sr[s4];
#pragma unroll
    for (int q = 0; q < 4; ++q)
      lg[q] += sv.x * Qs[q][8 + 4 * s4] + sv.y * Qs[q][9 + 4 * s4]
             + sv.z * Qs[q][10 + 4 * s4] + sv.w * Qs[q][11 + 4 * s4];
  }
  wlds[t] = make_float4(lg[0], lg[1], lg[2], lg[3]);

  float lmax[4];
#pragma unroll
  for (int q = 0; q < 4; ++q) lmax[q] = lg[q];
#pragma unroll
  for (int off = 32; off; off >>= 1)
#pragma unroll
    for (int q = 0; q < 4; ++q) lmax[q] = fmaxf(lmax[q], __shfl_xor(lmax[q], off));
  if (lane == 0)
#pragma unroll
    for (int q = 0; q < 4; ++q) red[q][wave] = lmax[q];
  __syncthreads();
  if (t < 4) mfin[t] = fmaxf(fmaxf(red[t][0], red[t][1]), fmaxf(red[t][2], red[t][3]));
  __syncthreads();

  float4 wv = wlds[t];
  wv.x = __expf(wv.x - mfin[0]);
  wv.y = __expf(wv.y - mfin[1]);
  wv.z = __expf(wv.z - mfin[2]);
  wv.w = __expf(wv.w - mfin[3]);
  wlds[t] = wv;
  float lsum[4] = {wv.x, wv.y, wv.z, wv.w};
#pragma unroll
  for (int off = 32; off; off >>= 1)
#pragma unroll
    for (int q = 0; q < 4; ++q) lsum[q] += __shfl_xor(lsum[q], off);
  if (lane == 0)
#pragma unroll
    for (int q = 0; q < 4; ++q) red[q][wave] = lsum[q];
  __syncthreads();
  if (t < 4) lfin[t] = red[t][0] + red[t][1] + red[t][2] + red[t][3];
  __syncthreads();

  // ---- phase B: weighted V accumulation, float4 channel blocks, 8-deep batches ----
  // wave w: positions [w*64, w*64+64) (its own wlds slice). lane<30: x ch 8+4l..+3;
  // lane 30..45: S ch 4(l-30)..; lanes 46+ idle (exec-masked).
  const int pbeg = wave * 64;
  const bool active = lane < 46;
  const float* vbase = xp;
  int vstride = 0;
  if (lane < 30)      { vbase = xp + (size_t)(base + pbeg) * 128 + 8 + 4 * lane; vstride = 128; }
  else if (lane < 46) { vbase = S  + (size_t)(base + pbeg) * 64 + 4 * (lane - 30); vstride = 64; }

  if (active) {
    float4 aq0 = make_float4(0.f, 0.f, 0.f, 0.f);
    float4 aq1 = aq0, aq2 = aq0, aq3 = aq0;
#pragma unroll
    for (int b = 0; b < 8; ++b) {
      // issue 8 independent loads back-to-back
      float4 v0 = *reinterpret_cast<const float4*>(vbase + (size_t)(b * 8 + 0) * vstride);
      float4 v1 = *reinterpret_cast<const float4*>(vbase + (size_t)(b * 8 + 1) * vstride);
      float4 v2 = *reinterpret_cast<const float4*>(vbase + (size_t)(b * 8 + 2) * vstride);
      float4 v3 = *reinterpret_cast<const float4*>(vbase + (size_t)(b * 8 + 3) * vstride);
      float4 v4 = *reinterpret_cast<const float4*>(vbase + (size_t)(b * 8 + 4) * vstride);
      float4 v5 = *reinterpret_cast<const float4*>(vbase + (size_t)(b * 8 + 5) * vstride);
      float4 v6 = *reinterpret_cast<const float4*>(vbase + (size_t)(b * 8 + 6) * vstride);
      float4 v7 = *reinterpret_cast<const float4*>(vbase + (size_t)(b * 8 + 7) * vstride);
#define ACC(VV, II)                                                             \
      {                                                                         \
        float4 w = wlds[pbeg + b * 8 + II];                                     \
        aq0.x += w.x * VV.x; aq0.y += w.x * VV.y; aq0.z += w.x * VV.z; aq0.w += w.x * VV.w; \
        aq1.x += w.y * VV.x; aq1.y += w.y * VV.y; aq1.z += w.y * VV.z; aq1.w += w.y * VV.w; \
        aq2.x += w.z * VV.x; aq2.y += w.z * VV.y; aq2.z += w.z * VV.z; aq2.w += w.z * VV.w; \
        aq3.x += w.w * VV.x; aq3.y += w.w * VV.y; aq3.z += w.w * VV.z; aq3.w += w.w * VV.w; \
      }
      ACC(v0, 0) ACC(v1, 1) ACC(v2, 2) ACC(v3, 3)
      ACC(v4, 4) ACC(v5, 5) ACC(v6, 6) ACC(v7, 7)
#undef ACC
    }
    *reinterpret_cast<float4*>(&part[wave][0][4 * lane]) = aq0;
    *reinterpret_cast<float4*>(&part[wave][1][4 * lane]) = aq1;
    *reinterpret_cast<float4*>(&part[wave][2][4 * lane]) = aq2;
    *reinterpret_cast<float4*>(&part[wave][3][4 * lane]) = aq3;
  }
  __syncthreads();

  const size_t po = ((size_t)n * NCH + ch) * PSTRIDE;
  if (t < 4) { P[po + t] = mfin[t]; P[po + 4 + t] = lfin[t]; }
  for (int idx = t; idx < 736; idx += 256) {
    const int q = idx / 184, d = idx - q * 184;
    P[po + 8 + idx] = (part[0][q][d] + part[1][q][d]) + (part[2][q][d] + part[3][q][d]);
  }
}

// ---------------------------------------------------------------- attention combine
__global__ __launch_bounds__(256) void k_attn_comb(
    const float* __restrict__ P, const float* __restrict__ pQ,
    const float* __restrict__ q_b2, const int* __restrict__ cptr,
    const float* __restrict__ r_prev, const float* __restrict__ a_prev,
    float* __restrict__ ans) {
  const int n = blockIdx.x, t = threadIdx.x;
  __shared__ float sc[NCH][4];
  if (t < 4) {
    const int q = t;
    float M = -1e30f;
    for (int c = 0; c < NCH; ++c) M = fmaxf(M, P[((size_t)n * NCH + c) * PSTRIDE + q]);
    float L = 0.f;
    for (int c = 0; c < NCH; ++c) {
      const size_t po = ((size_t)n * NCH + c) * PSTRIDE;
      L += P[po + 4 + q] * __expf(P[po + q] - M);
    }
    const float inv = 1.f / L;
    for (int c = 0; c < NCH; ++c) {
      const size_t po = ((size_t)n * NCH + c) * PSTRIDE;
      sc[c][q] = __expf(P[po + q] - M) * inv;
    }
  }
  __syncthreads();
  const int coff = cptr[0] * 288;
  float* ap = ans + (size_t)n * 1026;
  for (int idx = t; idx < 1026; idx += 256) {
    float val;
    if (idx < 736) {
      const int q = idx / 184, d = idx - q * 184;
      float s = 0.f;
#pragma unroll
      for (int c = 0; c < NCH; ++c)
        s += P[((size_t)n * NCH + c) * PSTRIDE + 8 + q * 184 + d] * sc[c][q];
      val = s;
    } else if (idx < 1024) {
      const int qi = idx - 736;
      float s = q_b2[coff + qi];
#pragma unroll
      for (int z = 0; z < 8; ++z) s += pQ[((size_t)z * NTOT + n) * 288 + qi];
      val = s;
    } else if (idx == 1024) {
      val = r_prev[n];
    } else {
      val = a_prev[n];
    }
    ap[idx] = val;
  }
}

// ---------------------------------------------------------------- LSTM gates (fused a-mlp out reduce, z=8)
__global__ __launch_bounds__(256) void k_gates(
    const float* __restrict__ pA, const float* __restrict__ biasA,
    const float* __restrict__ hp,
    const float* __restrict__ w_ih, const float* __restrict__ w_hh,
    const float* __restrict__ b_ih, const float* __restrict__ b_hh,
    float* __restrict__ gbuf) {
  const int t = threadIdx.x;
  const int n0 = blockIdx.x * 2;
  const int r0 = blockIdx.y * 64;
  __shared__ float xs[2][256], hs[2][256];
  __shared__ float red[64][4][5];
#pragma unroll
  for (int s = 0; s < 2; ++s) {
    float v0 = biasA[t], v1 = 0.f, v2 = 0.f, v3 = 0.f;
#pragma unroll
    for (int z = 0; z < 8; z += 4) {
      v0 += pA[((size_t)(z + 0) * NTOT + n0 + s) * 256 + t];
      v1 += pA[((size_t)(z + 1) * NTOT + n0 + s) * 256 + t];
      v2 += pA[((size_t)(z + 2) * NTOT + n0 + s) * 256 + t];
      v3 += pA[((size_t)(z + 3) * NTOT + n0 + s) * 256 + t];
    }
    xs[s][t] = (v0 + v1) + (v2 + v3);
    hs[s][t] = hp[(size_t)(n0 + s) * 256 + t];
  }
  __syncthreads();
  const int r = t >> 2, kq = t & 3;
  const int row = r0 + r;
  const float4* wi = reinterpret_cast<const float4*>(w_ih + (size_t)row * 256 + kq * 64);
  const float4* wh = reinterpret_cast<const float4*>(w_hh + (size_t)row * 256 + kq * 64);
  float s00 = 0.f, s01 = 0.f, s10 = 0.f, s11 = 0.f;
#pragma unroll
  for (int i = 0; i < 16; ++i) {
    float4 a = wi[i], b = wh[i];
    const int k4 = kq * 64 + i * 4;
    s00 += a.x * xs[0][k4] + a.y * xs[0][k4 + 1] + a.z * xs[0][k4 + 2] + a.w * xs[0][k4 + 3];
    s01 += a.x * xs[1][k4] + a.y * xs[1][k4 + 1] + a.z * xs[1][k4 + 2] + a.w * xs[1][k4 + 3];
    s10 += b.x * hs[0][k4] + b.y * hs[0][k4 + 1] + b.z * hs[0][k4 + 2] + b.w * hs[0][k4 + 3];
    s11 += b.x * hs[1][k4] + b.y * hs[1][k4 + 1] + b.z * hs[1][k4 + 2] + b.w * hs[1][k4 + 3];
  }
  red[r][kq][0] = s00; red[r][kq][1] = s01; red[r][kq][2] = s10; red[r][kq][3] = s11;
  __syncthreads();
  if (t < 128) {
    const int rr = t >> 1, s = t & 1;
    float g = b_ih[r0 + rr] + b_hh[r0 + rr];
#pragma unroll
    for (int k = 0; k < 4; ++k) g += red[rr][k][s] + red[rr][k][2 + s];
    gbuf[(size_t)(n0 + s) * 1024 + r0 + rr] = g;
  }
}

// ---------------------------------------------------------------- LSTM elementwise + heads
__global__ __launch_bounds__(256) void k_lstm2(
    const float* __restrict__ gbuf, const float* __restrict__ cp,
    const float* __restrict__ p_w, const float* __restrict__ p_b,
    const float* __restrict__ v_w, const float* __restrict__ v_b,
    float* __restrict__ out) {
  const int t = threadIdx.x;
  const int n0 = blockIdx.x * 2;
  __shared__ float h2[2][256];
#pragma unroll
  for (int s = 0; s < 2; ++s) {
    const size_t gb = (size_t)(n0 + s) * 1024;
    float gi = gbuf[gb + t], gf = gbuf[gb + 256 + t];
    float gg = gbuf[gb + 512 + t], go = gbuf[gb + 768 + t];
    float si = 1.f / (1.f + __expf(-gi));
    float sf = 1.f / (1.f + __expf(-gf));
    float so = 1.f / (1.f + __expf(-go));
    float c2 = sf * cp[(size_t)(n0 + s) * 256 + t] + si * tanhf(gg);
    h2[s][t] = so * tanhf(c2);
  }
  __syncthreads();
  if (t < 72) {
    const int si = t / 36, r = t % 36, iv = r / 18, j = r % 18;
    const float* W = iv ? v_w : p_w;
    const float* B = iv ? v_b : p_b;
    float s = B[j];
#pragma unroll 8
    for (int k = 0; k < 256; ++k) s += h2[si][k] * W[k * 18 + j];
    out[(size_t)iv * (NTOT * 18) + (size_t)(n0 + si) * 18 + j] = s;
  }
}

// ---------------------------------------------------------------- launch
extern "C" void kernel_launch(void* const* d_in, const int* in_sizes, int n_in,
                              void* d_out, int out_size, void* d_ws, size_t ws_size,
                              hipStream_t stream) {
  const float* x      = (const float*)d_in[0];
  const int*   cptr   = (const int*)d_in[1];
  const float* r_prev = (const float*)d_in[2];
  const float* a_prev = (const float*)d_in[3];
  const float* hprev  = (const float*)d_in[4];
  const float* cprev  = (const float*)d_in[5];
  const float* q_w0 = (const float*)d_in[6];
  const float* q_b0 = (const float*)d_in[7];
  const float* q_w1 = (const float*)d_in[8];
  const float* q_b1 = (const float*)d_in[9];
  const float* q_w2 = (const float*)d_in[10];
  const float* q_b2 = (const float*)d_in[11];
  const float* a_w0 = (const float*)d_in[12];
  const float* a_b0 = (const float*)d_in[13];
  const float* a_w1 = (const float*)d_in[14];
  const float* a_b1 = (const float*)d_in[15];
  const float* a_w2 = (const float*)d_in[16];
  const float* a_b2 = (const float*)d_in[17];
  const float* w_ih = (const float*)d_in[18];
  const float* w_hh = (const float*)d_in[19];
  const float* b_ih = (const float*)d_in[20];
  const float* b_hh = (const float*)d_in[21];
  const float* p_w  = (const float*)d_in[22];
  const float* p_b  = (const float*)d_in[23];
  const float* v_w  = (const float*)d_in[24];
  const float* v_b  = (const float*)d_in[25];
  float* out = (float*)d_out;
  float* ws  = (float*)d_ws;

  // workspace layout (floats)
  float* Sb  = ws;                // 262144
  float* pQ  = Sb  + 262144;      // 294912  (8 x 128 x 288) q_w2 partials
  float* pb1 = pQ  + 294912;      // 589824  (9 x 128 x 512)
  float* pb2 = pb1 + 589824;      // 524288  (8 x 128 x 512)
  float* pb3 = pb2 + 524288;      // 262144  (8 x 128 x 256)
  float* Pp  = pb3 + 262144;      // 1523712 (2048 x 744) attn partials
  float* ans = Pp  + 1523712;     // 131328  (128 x 1026)
  float* gbuf= ans + 131328;      // 131072  (128 x 1024)

  k_sbasis<<<1024, 256, 0, stream>>>(Sb);

  // q-mlp: hprev(128,256) -> 512 -> 512 -> Q partials (288 cols at offset c*288)
  k_gemm<<<dim3(2, 32, 4), 256, 0, stream>>>(hprev, nullptr, nullptr, 0, 0,
                                             q_w0, pb1, 512, 256, 512, 64, cptr, 0);
  k_gemm<<<dim3(2, 32, 8), 256, 0, stream>>>(nullptr, pb1, q_b0, 4, 1,
                                             q_w1, pb2, 512, 512, 512, 64, cptr, 0);
  k_gemm<<<dim3(2, 32, 8), 256, 0, stream>>>(nullptr, pb2, q_b1, 8, 1,
                                             q_w2, pQ, 288, 512, 1152, 64, cptr, 288);

  // attention (Q reduced in-block from pQ, z=8)
  k_attn_part<<<dim3(NCH, NTOT), 256, 0, stream>>>(x, Sb, pQ, q_b2, cptr, Pp);
  k_attn_comb<<<NTOT, 256, 0, stream>>>(Pp, pQ, q_b2, cptr, r_prev, a_prev, ans);

  // a-mlp: ans(128,1026) -> 512 -> 512 -> 256
  k_gemm<<<dim3(2, 32, 9), 256, 0, stream>>>(ans, nullptr, nullptr, 0, 0,
                                             a_w0, pb1, 512, 1026, 512, 128, cptr, 0);
  k_gemm<<<dim3(2, 32, 8), 256, 0, stream>>>(nullptr, pb1, a_b0, 9, 1,
                                             a_w1, pb2, 512, 512, 512, 64, cptr, 0);
  k_gemm<<<dim3(1, 32, 8), 256, 0, stream>>>(nullptr, pb2, a_b1, 8, 1,
                                             a_w2, pb3, 256, 512, 256, 64, cptr, 0);

  // LSTM + heads (am reduced in-block from pb3, z=8)
  k_gates<<<dim3(64, 16), 256, 0, stream>>>(pb3, a_b2, hprev, w_ih, w_hh, b_ih, b_hh, gbuf);
  k_lstm2<<<64, 256, 0, stream>>>(gbuf, cprev, p_w, p_b, v_w, v_b, out);
}